// Round 3
// baseline (191.640 us; speedup 1.0000x reference)
//
#include <hip/hip_runtime.h>

// DigitCaps dynamic routing — single fused kernel (one block per batch),
// remapped from 256 -> 512 threads for 2 waves/SIMD latency hiding.
// Round-1 lesson: multi-dispatch costs ~8us/gap -> keep ONE dispatch.
// Round-2 lesson: grid.sync()/cooperative launch breaks under the harness's
// graph-capture replay -> no cross-block communication at all.
// Thread map: c = tid>>4 (0..31), slot = tid&15 (0..15), 9 hw per thread.

#define BB 128
#define CC 32
#define HWN 144   // 12*12
#define QQ 8      // IN_CAPS
#define OO 10     // OUT_CH
#define PP 16     // OUT_CAPS

__device__ __forceinline__ float squash16(float s) {
    // tid = o*16 + p : reduce s^2 over the 16 p-lanes (masks 1..8)
    float sn = s * s;
#pragma unroll
    for (int m = 1; m <= 8; m <<= 1) sn += __shfl_xor(sn, m);
    return s * (sqrtf(sn) / (1.f + sn));
}

__global__ __launch_bounds__(512, 2)
void digitcaps_routing(const float* __restrict__ x, const float* __restrict__ Wm,
                       float* __restrict__ out) {
    const int b    = blockIdx.x;
    const int tid  = threadIdx.x;
    const int c    = tid >> 4;   // 0..31
    const int slot = tid & 15;   // 0..15

    __shared__ float usum_s[CC * QQ];        // 1 KB
    __shared__ float Wv_s[CC * OO * QQ];     // 10 KB (running logit-weight acc)
    __shared__ float t_s[CC * OO * QQ];      // 10 KB
    __shared__ float v_s[OO * PP];           // 640 B

    const float* xc = x + ((size_t)b * CC + c) * (HWN * QQ);

    // ---- A: usum[c][q] = sum_hw x[b,c,hw,q] ----
    float us[QQ];
#pragma unroll
    for (int q = 0; q < QQ; ++q) us[q] = 0.f;
#pragma unroll
    for (int i = 0; i < 9; ++i) {            // 144 = 16 slots * 9
        const int hw = slot + (i << 4);
        const float4* p4 = (const float4*)(xc + hw * QQ);
        float4 a = p4[0], d = p4[1];
        us[0] += a.x; us[1] += a.y; us[2] += a.z; us[3] += a.w;
        us[4] += d.x; us[5] += d.y; us[6] += d.z; us[7] += d.w;
    }
#pragma unroll
    for (int m = 1; m <= 8; m <<= 1) {       // reduce over 16 slot lanes
#pragma unroll
        for (int q = 0; q < QQ; ++q) us[q] += __shfl_xor(us[q], m);
    }
    if (slot == 0) {
#pragma unroll
        for (int q = 0; q < QQ; ++q) usum_s[c * QQ + q] = us[q];
    }
    __syncthreads();

    // ---- B: v1 = squash(0.1 * Wm . usum)  (iter-1 c_ij is uniform 0.1) ----
    if (tid < OO * PP) {
        const int o = tid >> 4, p = tid & 15;
        float s = 0.f;
        for (int cc = 0; cc < CC; ++cc) {
            const float4* w4 = (const float4*)(Wm + (((cc * OO + o) * PP + p) * QQ));
            float4 w0 = w4[0], w1 = w4[1];
            const float* u0 = &usum_s[cc * QQ];
            s += w0.x * u0[0] + w0.y * u0[1] + w0.z * u0[2] + w0.w * u0[3]
               + w1.x * u0[4] + w1.y * u0[5] + w1.z * u0[6] + w1.w * u0[7];
        }
        s *= 0.1f;
        v_s[tid] = squash16(s);
    }
    __syncthreads();

    // ---- Wv_s = Wm . v1  (logit accumulator; b_ij additivity) ----
    if (tid < CC * OO) {
        const int cc = tid / OO, o = tid - cc * OO;
        float acc[QQ];
#pragma unroll
        for (int q = 0; q < QQ; ++q) acc[q] = 0.f;
        const float* wp = Wm + ((cc * OO + o) * PP) * QQ;
#pragma unroll
        for (int p = 0; p < PP; ++p) {
            const float vv = v_s[o * PP + p];
            const float4* w4 = (const float4*)(wp + p * QQ);
            float4 w0 = w4[0], w1 = w4[1];
            acc[0] += vv * w0.x; acc[1] += vv * w0.y; acc[2] += vv * w0.z; acc[3] += vv * w0.w;
            acc[4] += vv * w1.x; acc[5] += vv * w1.y; acc[6] += vv * w1.z; acc[7] += vv * w1.w;
        }
        float* dst = Wv_s + (cc * OO + o) * QQ;
#pragma unroll
        for (int q = 0; q < QQ; ++q) dst[q] = acc[q];
    }
    __syncthreads();

    // ---- Routing iterations 2 and 3 ----
    for (int iter = 0; iter < 2; ++iter) {
        // logit weights for this thread's c
        float wv[OO][QQ];
#pragma unroll
        for (int o = 0; o < OO; ++o)
#pragma unroll
            for (int q = 0; q < QQ; ++q) wv[o][q] = Wv_s[(c * OO + o) * QQ + q];

        float tl[OO][QQ];
#pragma unroll
        for (int o = 0; o < OO; ++o)
#pragma unroll
            for (int q = 0; q < QQ; ++q) tl[o][q] = 0.f;

#pragma unroll
        for (int i = 0; i < 9; ++i) {        // 9 hw per thread
            const int hw = slot + (i << 4);
            const float4* p4 = (const float4*)(xc + hw * QQ);
            float4 a = p4[0], d = p4[1];
            float u[QQ] = {a.x, a.y, a.z, a.w, d.x, d.y, d.z, d.w};
            float lg[OO];
            float mx = -1e30f;
#pragma unroll
            for (int o = 0; o < OO; ++o) {
                float t = 0.f;
#pragma unroll
                for (int q = 0; q < QQ; ++q) t += u[q] * wv[o][q];
                lg[o] = t;
                mx = fmaxf(mx, t);
            }
            float ssum = 0.f;
#pragma unroll
            for (int o = 0; o < OO; ++o) { lg[o] = __expf(lg[o] - mx); ssum += lg[o]; }
            const float inv = 1.f / ssum;
#pragma unroll
            for (int o = 0; o < OO; ++o) {
                const float cij = lg[o] * inv;
#pragma unroll
                for (int q = 0; q < QQ; ++q) tl[o][q] += cij * u[q];
            }
        }
        // reduce t over the 16 slot lanes
#pragma unroll
        for (int m = 1; m <= 8; m <<= 1) {
#pragma unroll
            for (int o = 0; o < OO; ++o)
#pragma unroll
                for (int q = 0; q < QQ; ++q) tl[o][q] += __shfl_xor(tl[o][q], m);
        }
        if (slot == 0) {
#pragma unroll
            for (int o = 0; o < OO; ++o)
#pragma unroll
                for (int q = 0; q < QQ; ++q) t_s[(c * OO + o) * QQ + q] = tl[o][q];
        }
        __syncthreads();

        // s[o,p] = sum_{c,q} Wm[c,o,p,q]*t[c,o,q] ; v = squash(s)
        if (tid < OO * PP) {
            const int o = tid >> 4, p = tid & 15;
            float s = 0.f;
            for (int cc = 0; cc < CC; ++cc) {
                const float4* w4 = (const float4*)(Wm + (((cc * OO + o) * PP + p) * QQ));
                float4 w0 = w4[0], w1 = w4[1];
                const float4* t4 = (const float4*)(t_s + (cc * OO + o) * QQ);
                float4 t0 = t4[0], t1 = t4[1];
                s += w0.x * t0.x + w0.y * t0.y + w0.z * t0.z + w0.w * t0.w
                   + w1.x * t1.x + w1.y * t1.y + w1.z * t1.z + w1.w * t1.w;
            }
            const float v = squash16(s);
            if (iter == 1) out[(size_t)b * (OO * PP) + tid] = v;
            else           v_s[tid] = v;
        }
        if (iter == 0) {
            __syncthreads();
            // Wv_s += Wm . v2
            if (tid < CC * OO) {
                const int cc = tid / OO, o = tid - cc * OO;
                float acc[QQ];
#pragma unroll
                for (int q = 0; q < QQ; ++q) acc[q] = 0.f;
                const float* wp = Wm + ((cc * OO + o) * PP) * QQ;
#pragma unroll
                for (int p = 0; p < PP; ++p) {
                    const float vv = v_s[o * PP + p];
                    const float4* w4 = (const float4*)(wp + p * QQ);
                    float4 w0 = w4[0], w1 = w4[1];
                    acc[0] += vv * w0.x; acc[1] += vv * w0.y; acc[2] += vv * w0.z; acc[3] += vv * w0.w;
                    acc[4] += vv * w1.x; acc[5] += vv * w1.y; acc[6] += vv * w1.z; acc[7] += vv * w1.w;
                }
                float* dst = Wv_s + (cc * OO + o) * QQ;
#pragma unroll
                for (int q = 0; q < QQ; ++q) dst[q] += acc[q];
            }
            __syncthreads();
        }
    }
}

extern "C" void kernel_launch(void* const* d_in, const int* in_sizes, int n_in,
                              void* d_out, int out_size, void* d_ws, size_t ws_size,
                              hipStream_t stream) {
    const float* x  = (const float*)d_in[0];   // [128,32,12,12,8]
    const float* Wm = (const float*)d_in[1];   // [1,1,32,10,16,8]
    float* out      = (float*)d_out;           // [128,10,16]
    digitcaps_routing<<<BB, 512, 0, stream>>>(x, Wm, out);
}

// Round 4
// 172.176 us; speedup vs baseline: 1.1130x; 1.1130x over previous
//
#include <hip/hip_runtime.h>

// DigitCaps dynamic routing — single kernel, c-split across 512 blocks with a
// hand-rolled grid barrier (cooperative launch breaks under graph capture;
// multi-dispatch costs ~8us/gap; 512-thread blocks spill at VGPR<=128).
//
// Grid (NGRP=4, BB=128) = 512 blocks x 256 threads = exactly 2 blocks/CU:
//   VGPR cap 256 via __launch_bounds__(256,2) (kernel needs ~160, no spill),
//   LDS ~6KB/block -> aggregate capacity 512 = grid -> all blocks co-resident
//   -> spin barrier is deadlock-free.
// Each block owns CL=8 channels of one batch element; t-reduction (over hw)
// stays block-local; only 160-float s-partials cross blocks (3 barriers).
// Barrier: monotone ticket counters (8 leaves + root), self-consistent across
// graph replays (each launch advances counts by exactly one full round).

#define BB 128
#define CC 32
#define HWN 144   // 12*12
#define QQ 8      // IN_CAPS
#define OO 10     // OUT_CH
#define PP 16     // OUT_CAPS
#define NGRP 4    // c groups
#define CL 8      // channels per group
#define NBLK (NGRP * BB)      // 512
#define NLEAF 8
#define LPB (NBLK / NLEAF)    // 64 blocks per leaf

__device__ unsigned g_leaf[NLEAF * 32];   // 128B-strided leaf counters
__device__ unsigned g_root = 0;
__device__ float g_ps[3 * BB * NGRP * OO * PP];   // s-partials per iter

__device__ __forceinline__ void gbarrier(int leaf) {
    __syncthreads();
    if (threadIdx.x == 0) {
        __threadfence();   // agent-scope release: flush our L2 writes
        unsigned t = __hip_atomic_fetch_add(&g_leaf[leaf * 32], 1u,
                         __ATOMIC_ACQ_REL, __HIP_MEMORY_SCOPE_AGENT);
        if ((t % LPB) == LPB - 1)
            __hip_atomic_fetch_add(&g_root, 1u,
                         __ATOMIC_ACQ_REL, __HIP_MEMORY_SCOPE_AGENT);
        const unsigned target = (t / LPB + 1u) * NLEAF;
        while (__hip_atomic_load(&g_root, __ATOMIC_RELAXED,
                                 __HIP_MEMORY_SCOPE_AGENT) < target)
            __builtin_amdgcn_s_sleep(1);
        __threadfence();   // acquire: invalidate L1/L2 before cross-block reads
    }
    __syncthreads();
}

__device__ __forceinline__ float squash16(float s) {
    // tid = o*16 + p : reduce s^2 over the 16 p-lanes
    float sn = s * s;
#pragma unroll
    for (int m = 1; m <= 8; m <<= 1) sn += __shfl_xor(sn, m);
    return s * (sqrtf(sn) / (1.f + sn));
}

__global__ __launch_bounds__(256, 2)
void digitcaps_routing(const float* __restrict__ x, const float* __restrict__ Wm,
                       float* __restrict__ out) {
    const int grp  = blockIdx.x;                 // 0..3
    const int b    = blockIdx.y;                 // 0..127
    const int leaf = (blockIdx.x + (blockIdx.y << 2)) & (NLEAF - 1);
    const int tid  = threadIdx.x;
    const int cl   = tid >> 5;                   // 0..7 local channel
    const int slot = tid & 31;                   // 0..31

    __shared__ float usum_s[CL * QQ];            // 256 B
    __shared__ float Wv_s[CL * OO * QQ];         // 2.5 KB (logit-weight acc)
    __shared__ float t_s[CL * OO * QQ];          // 2.5 KB
    __shared__ float v_s[OO * PP];               // 640 B

    const float* xc = x + ((size_t)b * CC + grp * CL + cl) * (HWN * QQ);
    const float* wg = Wm + (size_t)grp * CL * OO * PP * QQ;

    // ---- A: local usum[cl][q] = sum_hw u ----
    {
        float us[QQ];
#pragma unroll
        for (int q = 0; q < QQ; ++q) us[q] = 0.f;
#pragma unroll
        for (int i = 0; i < 5; ++i) {            // 144 = 32 slots * 4.5
            const int hw = slot + (i << 5);
            if (hw < HWN) {
                const float4* p4 = (const float4*)(xc + hw * QQ);
                float4 a = p4[0], d = p4[1];
                us[0] += a.x; us[1] += a.y; us[2] += a.z; us[3] += a.w;
                us[4] += d.x; us[5] += d.y; us[6] += d.z; us[7] += d.w;
            }
        }
#pragma unroll
        for (int m = 1; m <= 16; m <<= 1) {      // reduce over 32 slot lanes
#pragma unroll
            for (int q = 0; q < QQ; ++q) us[q] += __shfl_xor(us[q], m);
        }
        if (slot == 0) {
#pragma unroll
            for (int q = 0; q < QQ; ++q) usum_s[cl * QQ + q] = us[q];
        }
    }
    __syncthreads();

    // partial s1[o,p] = 0.1 * sum_{c in grp, q} Wm*usum
    if (tid < OO * PP) {
        const int o = tid >> 4, p = tid & 15;
        float s = 0.f;
#pragma unroll
        for (int cc = 0; cc < CL; ++cc) {
            const float4* w4 = (const float4*)(wg + (((cc * OO + o) * PP + p) * QQ));
            float4 w0 = w4[0], w1 = w4[1];
            const float* u0 = &usum_s[cc * QQ];
            s += w0.x * u0[0] + w0.y * u0[1] + w0.z * u0[2] + w0.w * u0[3]
               + w1.x * u0[4] + w1.y * u0[5] + w1.z * u0[6] + w1.w * u0[7];
        }
        g_ps[(size_t)((0 * BB + b) * NGRP + grp) * (OO * PP) + tid] = 0.1f * s;
    }
    gbarrier(leaf);

    // ---- routing iterations ----
    for (int iter = 0; iter < 2; ++iter) {
        // v = squash(sum of s-partials)
        if (tid < OO * PP) {
            float s = 0.f;
#pragma unroll
            for (int g = 0; g < NGRP; ++g)
                s += g_ps[(size_t)((iter * BB + b) * NGRP + g) * (OO * PP) + tid];
            v_s[tid] = squash16(s);
        }
        __syncthreads();

        // Wv (set on iter 0, accumulate on iter 1): local channels only
        if (tid < CL * OO) {
            const int cc = tid / OO, o = tid - cc * OO;
            float acc[QQ];
#pragma unroll
            for (int q = 0; q < QQ; ++q) acc[q] = 0.f;
            const float* wp = wg + ((cc * OO + o) * PP) * QQ;
#pragma unroll
            for (int p = 0; p < PP; ++p) {
                const float vv = v_s[o * PP + p];
                const float4* w4 = (const float4*)(wp + p * QQ);
                float4 w0 = w4[0], w1 = w4[1];
                acc[0] += vv * w0.x; acc[1] += vv * w0.y; acc[2] += vv * w0.z; acc[3] += vv * w0.w;
                acc[4] += vv * w1.x; acc[5] += vv * w1.y; acc[6] += vv * w1.z; acc[7] += vv * w1.w;
            }
            float* dst = Wv_s + (cc * OO + o) * QQ;
            if (iter == 0) {
#pragma unroll
                for (int q = 0; q < QQ; ++q) dst[q] = acc[q];
            } else {
#pragma unroll
                for (int q = 0; q < QQ; ++q) dst[q] += acc[q];
            }
        }
        __syncthreads();

        // heavy: logits = u.Wv, softmax over o, t = sum_hw c_ij*u
        float wv[OO][QQ];
#pragma unroll
        for (int o = 0; o < OO; ++o)
#pragma unroll
            for (int q = 0; q < QQ; ++q) wv[o][q] = Wv_s[(cl * OO + o) * QQ + q];

        float tl[OO][QQ];
#pragma unroll
        for (int o = 0; o < OO; ++o)
#pragma unroll
            for (int q = 0; q < QQ; ++q) tl[o][q] = 0.f;

#pragma unroll
        for (int i = 0; i < 5; ++i) {
            const int hw = slot + (i << 5);
            if (hw < HWN) {
                const float4* p4 = (const float4*)(xc + hw * QQ);
                float4 a = p4[0], d = p4[1];
                float u[QQ] = {a.x, a.y, a.z, a.w, d.x, d.y, d.z, d.w};
                float lg[OO];
                float mx = -1e30f;
#pragma unroll
                for (int o = 0; o < OO; ++o) {
                    float t = 0.f;
#pragma unroll
                    for (int q = 0; q < QQ; ++q) t += u[q] * wv[o][q];
                    lg[o] = t;
                    mx = fmaxf(mx, t);
                }
                float ssum = 0.f;
#pragma unroll
                for (int o = 0; o < OO; ++o) { lg[o] = __expf(lg[o] - mx); ssum += lg[o]; }
                const float inv = 1.f / ssum;
#pragma unroll
                for (int o = 0; o < OO; ++o) {
                    const float cij = lg[o] * inv;
#pragma unroll
                    for (int q = 0; q < QQ; ++q) tl[o][q] += cij * u[q];
                }
            }
        }
        // reduce t over the 32 slot lanes
#pragma unroll
        for (int m = 1; m <= 16; m <<= 1) {
#pragma unroll
            for (int o = 0; o < OO; ++o)
#pragma unroll
                for (int q = 0; q < QQ; ++q) tl[o][q] += __shfl_xor(tl[o][q], m);
        }
        if (slot == 0) {
#pragma unroll
            for (int o = 0; o < OO; ++o)
#pragma unroll
                for (int q = 0; q < QQ; ++q) t_s[(cl * OO + o) * QQ + q] = tl[o][q];
        }
        __syncthreads();

        // partial s[o,p] = sum_{c in grp, q} Wm * t
        if (tid < OO * PP) {
            const int o = tid >> 4, p = tid & 15;
            float s = 0.f;
#pragma unroll
            for (int cc = 0; cc < CL; ++cc) {
                const float4* w4 = (const float4*)(wg + (((cc * OO + o) * PP + p) * QQ));
                float4 w0 = w4[0], w1 = w4[1];
                const float4* t4 = (const float4*)(t_s + (cc * OO + o) * QQ);
                float4 t0 = t4[0], t1 = t4[1];
                s += w0.x * t0.x + w0.y * t0.y + w0.z * t0.z + w0.w * t0.w
                   + w1.x * t1.x + w1.y * t1.y + w1.z * t1.z + w1.w * t1.w;
            }
            g_ps[(size_t)(((iter + 1) * BB + b) * NGRP + grp) * (OO * PP) + tid] = s;
        }
        gbarrier(leaf);
    }

    // ---- final: v3 = squash(sum partials), grp 0 writes out ----
    if (grp == 0 && tid < OO * PP) {
        float s = 0.f;
#pragma unroll
        for (int g = 0; g < NGRP; ++g)
            s += g_ps[(size_t)((2 * BB + b) * NGRP + g) * (OO * PP) + tid];
        out[(size_t)b * (OO * PP) + tid] = squash16(s);
    }
}

extern "C" void kernel_launch(void* const* d_in, const int* in_sizes, int n_in,
                              void* d_out, int out_size, void* d_ws, size_t ws_size,
                              hipStream_t stream) {
    const float* x  = (const float*)d_in[0];   // [128,32,12,12,8]
    const float* Wm = (const float*)d_in[1];   // [1,1,32,10,16,8]
    float* out      = (float*)d_out;           // [128,10,16]
    digitcaps_routing<<<dim3(NGRP, BB), 256, 0, stream>>>(x, Wm, out);
}

// Round 5
// 169.304 us; speedup vs baseline: 1.1319x; 1.0170x over previous
//
#include <hip/hip_runtime.h>

// DigitCaps dynamic routing — single kernel, c-split across 512 blocks.
// Round-4 lesson: a 512-participant grid barrier costs ~30us/sync (serialized
// agent-scope RMWs on shared lines). But the dataflow only couples the NGRP=4
// blocks of one batch element -> per-batch ticket sync (~1-2us).
// Round-3 lesson: 512-thread blocks spill (VGPR<=128) -> keep 256 threads.
// Round-2 lesson: cooperative launch breaks under graph capture -> hand-rolled
// monotone-ticket sync (counters advance by exactly 3*NGRP per launch; safe
// across graph replays).
//
// Grid (NGRP=4, BB=128) = 512 blocks x 256 threads = 2 blocks/CU co-resident
// (LDS 6KB, VGPR 128 -> capacity >= grid; verified no-deadlock in round 4).
// Each block owns CL=8 channels of one batch element; t-reduction (over hw)
// stays block-local; only 160-float s-partials cross blocks (3 syncs).

#define BB 128
#define CC 32
#define HWN 144   // 12*12
#define QQ 8      // IN_CAPS
#define OO 10     // OUT_CH
#define PP 16     // OUT_CAPS
#define NGRP 4    // c groups
#define CL 8      // channels per group

__device__ unsigned g_arr[BB * 32];               // per-batch tickets, 128B stride
__device__ float g_ps[3 * BB * NGRP * OO * PP];   // s-partials per phase

// Sync the NGRP blocks of batch b. Monotone tickets: phase k of replay r sees
// counter pass from (3r+k)*NGRP to (3r+k+1)*NGRP. spin=0 -> post-only.
__device__ __forceinline__ void batch_sync(int b, int spin) {
    __syncthreads();
    if (threadIdx.x == 0) {
        __threadfence();   // release: make g_ps writes visible device-wide
        unsigned t = __hip_atomic_fetch_add(&g_arr[b * 32], 1u,
                         __ATOMIC_ACQ_REL, __HIP_MEMORY_SCOPE_AGENT);
        if (spin) {
            const unsigned target = (t / NGRP + 1u) * NGRP;
            while (__hip_atomic_load(&g_arr[b * 32], __ATOMIC_RELAXED,
                                     __HIP_MEMORY_SCOPE_AGENT) < target)
                __builtin_amdgcn_s_sleep(1);
            __threadfence();   // acquire: invalidate stale lines before reads
        }
    }
    __syncthreads();
}

__device__ __forceinline__ float squash16(float s) {
    // tid = o*16 + p : reduce s^2 over the 16 p-lanes
    float sn = s * s;
#pragma unroll
    for (int m = 1; m <= 8; m <<= 1) sn += __shfl_xor(sn, m);
    return s * (sqrtf(sn) / (1.f + sn));
}

__global__ __launch_bounds__(256, 2)
void digitcaps_routing(const float* __restrict__ x, const float* __restrict__ Wm,
                       float* __restrict__ out) {
    const int grp  = blockIdx.x;                 // 0..3
    const int b    = blockIdx.y;                 // 0..127
    const int tid  = threadIdx.x;
    const int cl   = tid >> 5;                   // 0..7 local channel
    const int slot = tid & 31;                   // 0..31

    __shared__ float usum_s[CL * QQ];            // 256 B
    __shared__ float Wv_s[CL * OO * QQ];         // 2.5 KB (logit-weight acc)
    __shared__ float t_s[CL * OO * QQ];          // 2.5 KB
    __shared__ float v_s[OO * PP];               // 640 B

    const float* xc = x + ((size_t)b * CC + grp * CL + cl) * (HWN * QQ);
    const float* wg = Wm + (size_t)grp * CL * OO * PP * QQ;

    // ---- A: local usum[cl][q] = sum_hw u ----
    {
        float us[QQ];
#pragma unroll
        for (int q = 0; q < QQ; ++q) us[q] = 0.f;
#pragma unroll
        for (int i = 0; i < 5; ++i) {            // 144 = 32 slots * 4.5
            const int hw = slot + (i << 5);
            if (hw < HWN) {
                const float4* p4 = (const float4*)(xc + hw * QQ);
                float4 a = p4[0], d = p4[1];
                us[0] += a.x; us[1] += a.y; us[2] += a.z; us[3] += a.w;
                us[4] += d.x; us[5] += d.y; us[6] += d.z; us[7] += d.w;
            }
        }
#pragma unroll
        for (int m = 1; m <= 16; m <<= 1) {      // reduce over 32 slot lanes
#pragma unroll
            for (int q = 0; q < QQ; ++q) us[q] += __shfl_xor(us[q], m);
        }
        if (slot == 0) {
#pragma unroll
            for (int q = 0; q < QQ; ++q) usum_s[cl * QQ + q] = us[q];
        }
    }
    __syncthreads();

    // partial s1[o,p] = 0.1 * sum_{c in grp, q} Wm*usum
    if (tid < OO * PP) {
        const int o = tid >> 4, p = tid & 15;
        float s = 0.f;
#pragma unroll
        for (int cc = 0; cc < CL; ++cc) {
            const float4* w4 = (const float4*)(wg + (((cc * OO + o) * PP + p) * QQ));
            float4 w0 = w4[0], w1 = w4[1];
            const float* u0 = &usum_s[cc * QQ];
            s += w0.x * u0[0] + w0.y * u0[1] + w0.z * u0[2] + w0.w * u0[3]
               + w1.x * u0[4] + w1.y * u0[5] + w1.z * u0[6] + w1.w * u0[7];
        }
        g_ps[(size_t)((0 * BB + b) * NGRP + grp) * (OO * PP) + tid] = 0.1f * s;
    }
    batch_sync(b, 1);

    // ---- routing iterations ----
    for (int iter = 0; iter < 2; ++iter) {
        // v = squash(sum of s-partials)
        if (tid < OO * PP) {
            float s = 0.f;
#pragma unroll
            for (int g = 0; g < NGRP; ++g)
                s += g_ps[(size_t)((iter * BB + b) * NGRP + g) * (OO * PP) + tid];
            v_s[tid] = squash16(s);
        }
        __syncthreads();

        // Wv (set on iter 0, accumulate on iter 1): local channels only
        if (tid < CL * OO) {
            const int cc = tid / OO, o = tid - cc * OO;
            float acc[QQ];
#pragma unroll
            for (int q = 0; q < QQ; ++q) acc[q] = 0.f;
            const float* wp = wg + ((cc * OO + o) * PP) * QQ;
#pragma unroll
            for (int p = 0; p < PP; ++p) {
                const float vv = v_s[o * PP + p];
                const float4* w4 = (const float4*)(wp + p * QQ);
                float4 w0 = w4[0], w1 = w4[1];
                acc[0] += vv * w0.x; acc[1] += vv * w0.y; acc[2] += vv * w0.z; acc[3] += vv * w0.w;
                acc[4] += vv * w1.x; acc[5] += vv * w1.y; acc[6] += vv * w1.z; acc[7] += vv * w1.w;
            }
            float* dst = Wv_s + (cc * OO + o) * QQ;
            if (iter == 0) {
#pragma unroll
                for (int q = 0; q < QQ; ++q) dst[q] = acc[q];
            } else {
#pragma unroll
                for (int q = 0; q < QQ; ++q) dst[q] += acc[q];
            }
        }
        __syncthreads();

        // heavy: logits = u.Wv, softmax over o, t = sum_hw c_ij*u
        float wv[OO][QQ];
#pragma unroll
        for (int o = 0; o < OO; ++o)
#pragma unroll
            for (int q = 0; q < QQ; ++q) wv[o][q] = Wv_s[(cl * OO + o) * QQ + q];

        float tl[OO][QQ];
#pragma unroll
        for (int o = 0; o < OO; ++o)
#pragma unroll
            for (int q = 0; q < QQ; ++q) tl[o][q] = 0.f;

#pragma unroll
        for (int i = 0; i < 5; ++i) {
            const int hw = slot + (i << 5);
            if (hw < HWN) {
                const float4* p4 = (const float4*)(xc + hw * QQ);
                float4 a = p4[0], d = p4[1];
                float u[QQ] = {a.x, a.y, a.z, a.w, d.x, d.y, d.z, d.w};
                float lg[OO];
                float mx = -1e30f;
#pragma unroll
                for (int o = 0; o < OO; ++o) {
                    float t = 0.f;
#pragma unroll
                    for (int q = 0; q < QQ; ++q) t += u[q] * wv[o][q];
                    lg[o] = t;
                    mx = fmaxf(mx, t);
                }
                float ssum = 0.f;
#pragma unroll
                for (int o = 0; o < OO; ++o) { lg[o] = __expf(lg[o] - mx); ssum += lg[o]; }
                const float inv = 1.f / ssum;
#pragma unroll
                for (int o = 0; o < OO; ++o) {
                    const float cij = lg[o] * inv;
#pragma unroll
                    for (int q = 0; q < QQ; ++q) tl[o][q] += cij * u[q];
                }
            }
        }
        // reduce t over the 32 slot lanes
#pragma unroll
        for (int m = 1; m <= 16; m <<= 1) {
#pragma unroll
            for (int o = 0; o < OO; ++o)
#pragma unroll
                for (int q = 0; q < QQ; ++q) tl[o][q] += __shfl_xor(tl[o][q], m);
        }
        if (slot == 0) {
#pragma unroll
            for (int o = 0; o < OO; ++o)
#pragma unroll
                for (int q = 0; q < QQ; ++q) t_s[(cl * OO + o) * QQ + q] = tl[o][q];
        }
        __syncthreads();

        // partial s[o,p] = sum_{c in grp, q} Wm * t
        if (tid < OO * PP) {
            const int o = tid >> 4, p = tid & 15;
            float s = 0.f;
#pragma unroll
            for (int cc = 0; cc < CL; ++cc) {
                const float4* w4 = (const float4*)(wg + (((cc * OO + o) * PP + p) * QQ));
                float4 w0 = w4[0], w1 = w4[1];
                const float4* t4 = (const float4*)(t_s + (cc * OO + o) * QQ);
                float4 t0 = t4[0], t1 = t4[1];
                s += w0.x * t0.x + w0.y * t0.y + w0.z * t0.z + w0.w * t0.w
                   + w1.x * t1.x + w1.y * t1.y + w1.z * t1.z + w1.w * t1.w;
            }
            g_ps[(size_t)(((iter + 1) * BB + b) * NGRP + grp) * (OO * PP) + tid] = s;
        }
        // last phase: only grp 0 (the output writer) needs to wait
        batch_sync(b, (iter == 0) ? 1 : (grp == 0));
    }

    // ---- final: v3 = squash(sum partials), grp 0 writes out ----
    if (grp == 0 && tid < OO * PP) {
        float s = 0.f;
#pragma unroll
        for (int g = 0; g < NGRP; ++g)
            s += g_ps[(size_t)((2 * BB + b) * NGRP + g) * (OO * PP) + tid];
        out[(size_t)b * (OO * PP) + tid] = squash16(s);
    }
}

extern "C" void kernel_launch(void* const* d_in, const int* in_sizes, int n_in,
                              void* d_out, int out_size, void* d_ws, size_t ws_size,
                              hipStream_t stream) {
    const float* x  = (const float*)d_in[0];   // [128,32,12,12,8]
    const float* Wm = (const float*)d_in[1];   // [1,1,32,10,16,8]
    float* out      = (float*)d_out;           // [128,10,16]
    digitcaps_routing<<<dim3(NGRP, BB), 256, 0, stream>>>(x, Wm, out);
}